// Round 4
// baseline (354.936 us; speedup 1.0000x reference)
//
#include <hip/hip_runtime.h>
#include <math.h>

#define BB   1024
#define DD   768
#define HIDV 384
#define MLPH 300
#define MLPP 320   // padded to multiple of 64

typedef float v2f __attribute__((ext_vector_type(2)));

__device__ __forceinline__ float softplusf(float x) {
    return (x > 20.f) ? x : log1pf(expf(x));
}

// ---------------- init: zero accumulators (accum[16] + sumexp[1024]) ----------------
__global__ void k_init(float* __restrict__ ws) {
    int i = blockIdx.x * 256 + threadIdx.x;
    if (i < 16 + BB) ws[i] = 0.f;
}

// ---------------- A: z-reduce + sample + KL (UNCHANGED control, r2/r3) ----------------
// Pinned at ~73us across 18-55% occupancy: per-CU streaming cap, not waves.
__global__ __launch_bounds__(384, 6) void k_rs(
    const float* __restrict__ zl, const float* __restrict__ zv,
    const float* __restrict__ wl, const float* __restrict__ blp,
    const float* __restrict__ wv, const float* __restrict__ bvp,
    const float* __restrict__ eps1, const float* __restrict__ eps2,
    float* __restrict__ s1, float* __restrict__ s2, float* __restrict__ accum)
{
    __shared__ float SG[768];    // sig1 [0,384), sig2 [384,768)
    __shared__ float MU2[384];
    __shared__ float pr[6];
    int tid = threadIdx.x;       // 0..383
    int b = blockIdx.x;
    int g = tid / 96;            // 0..3
    int c = tid - g * 96;        // 0..95

    const float4* p;
    if (g < 2) p = (const float4*)(zl + (size_t)b * 15360) + ((g & 1) * 96 + c);
    else       p = (const float4*)(zv + (size_t)b * 27648) + ((g & 1) * 96 + c);

    float acc[4] = {0.f, 0.f, 0.f, 0.f};
    if (g < 2) {
        #pragma unroll
        for (int t0 = 0; t0 < 20; t0 += 10) {
            float4 vb[10];
            #pragma unroll
            for (int u = 0; u < 10; ++u) vb[u] = p[(t0 + u) * 192];
            #pragma unroll
            for (int u = 0; u < 10; ++u) {
                float w = wl[t0 + u];
                acc[0] = fmaf(vb[u].x, w, acc[0]);
                acc[1] = fmaf(vb[u].y, w, acc[1]);
                acc[2] = fmaf(vb[u].z, w, acc[2]);
                acc[3] = fmaf(vb[u].w, w, acc[3]);
            }
        }
    } else {
        #pragma unroll
        for (int t0 = 0; t0 < 36; t0 += 9) {
            float4 vb[9];
            #pragma unroll
            for (int u = 0; u < 9; ++u) vb[u] = p[(t0 + u) * 192];
            #pragma unroll
            for (int u = 0; u < 9; ++u) {
                float w = wv[t0 + u];
                acc[0] = fmaf(vb[u].x, w, acc[0]);
                acc[1] = fmaf(vb[u].y, w, acc[1]);
                acc[2] = fmaf(vb[u].z, w, acc[2]);
                acc[3] = fmaf(vb[u].w, w, acc[3]);
            }
        }
    }

    float bl = blp[0], bv = bvp[0];

    if (g == 1) {                 // sig1
        float4 o;
        o.x = softplusf(acc[0] + bl) + 1e-7f;
        o.y = softplusf(acc[1] + bl) + 1e-7f;
        o.z = softplusf(acc[2] + bl) + 1e-7f;
        o.w = softplusf(acc[3] + bl) + 1e-7f;
        *(float4*)(SG + c * 4) = o;
    } else if (g == 2) {          // mu2
        *(float4*)(MU2 + c * 4) =
            make_float4(acc[0] + bv, acc[1] + bv, acc[2] + bv, acc[3] + bv);
    } else if (g == 3) {          // sig2
        float4 o;
        o.x = softplusf(acc[0] + bv) + 1e-7f;
        o.y = softplusf(acc[1] + bv) + 1e-7f;
        o.z = softplusf(acc[2] + bv) + 1e-7f;
        o.w = softplusf(acc[3] + bv) + 1e-7f;
        *(float4*)(SG + 384 + c * 4) = o;
    }
    __syncthreads();

    float con = 0.f;
    if (g == 0) {
        float4 e1v = ((const float4*)eps1)[b * 96 + c];
        float4 e2v = ((const float4*)eps2)[b * 96 + c];
        float4 g1 = *(const float4*)(SG + c * 4);
        float4 m2 = *(const float4*)(MU2 + c * 4);
        float4 g2 = *(const float4*)(SG + 384 + c * 4);
        float e1a[4] = {e1v.x, e1v.y, e1v.z, e1v.w};
        float e2a[4] = {e2v.x, e2v.y, e2v.z, e2v.w};
        float g1a[4] = {g1.x, g1.y, g1.z, g1.w};
        float g2a[4] = {g2.x, g2.y, g2.z, g2.w};
        float m2a[4] = {m2.x, m2.y, m2.z, m2.w};
        float s1o[4], s2o[4];
        #pragma unroll
        for (int j = 0; j < 4; ++j) {
            float mu1 = acc[j] + bl;
            float mu2 = m2a[j];
            float sg1 = g1a[j], sg2 = g2a[j];
            float e1 = e1a[j], e2 = e2a[j];
            float sv1 = fmaf(sg1, e1, mu1);
            float sv2 = fmaf(sg2, e2, mu2);
            s1o[j] = sv1; s2o[j] = sv2;
            float z12 = (sv1 - mu2) / sg2;
            float z21 = (sv2 - mu1) / sg1;
            con += -0.5f * (e1 * e1 + e2 * e2) + 0.5f * z12 * z12 + 0.5f * z21 * z21;
        }
        ((float4*)s1)[b * 96 + c] = make_float4(s1o[0], s1o[1], s1o[2], s1o[3]);
        ((float4*)s2)[b * 96 + c] = make_float4(s2o[0], s2o[1], s2o[2], s2o[3]);
    }

    #pragma unroll
    for (int m = 1; m < 64; m <<= 1) con += __shfl_xor(con, m);
    if ((tid & 63) == 0) pr[tid >> 6] = con;
    __syncthreads();
    if (tid == 0)
        atomicAdd(&accum[0], pr[0] + pr[1] + pr[2] + pr[3] + pr[4] + pr[5]);
}

// ---------------- B: Axb = s1 @ W1x^T + b1, By = s2 @ W1y^T ----------------
// 32b x 16n tile, 128 thr, 4 outputs/thread (2b x 2n), grid (32,20,2) = 1280
// blocks = 5/CU even. Inner loop: 2 conflict-free v2f LDS reads + 2 pk_fma
// per h -> ~8-10us est (r3 version was LDS-issue-bound, est 25-40us).
__global__ __launch_bounds__(128) void k_gemm(
    const float* __restrict__ s1, const float* __restrict__ s2,
    const float* __restrict__ W1, const float* __restrict__ b1,
    float* __restrict__ Axb, float* __restrict__ By)
{
    __shared__ float Ss[64][34];   // [h][b], pad 34: read CF, store 2-way
    __shared__ float Ws[64][18];   // [h][n]
    int z = blockIdx.z;
    const float* S = z ? s2 : s1;
    float* Out = z ? By : Axb;
    int wofs = z ? HIDV : 0;
    int b0 = blockIdx.x * 32;
    int n0 = blockIdx.y * 16;
    int tid = threadIdx.x;
    int srow = tid & 31, sq = tid >> 5;    // S loader: rows span banks (CF stores)
    int wrow = tid >> 3, wq = tid & 7;     // W loader: 16 rows x {wq, wq+8} f4
    int nrow = n0 + wrow;
    int bp = tid & 15, np = tid >> 4;      // outputs: b=b0+bp*2+{0,1}, n=n0+np*2+{0,1}

    float4 ps[4], pw[2];
    auto ld = [&](int hc) {
        #pragma unroll
        for (int u = 0; u < 4; ++u)
            ps[u] = *(const float4*)&S[(b0 + srow) * HIDV + hc + (sq + 4 * u) * 4];
        #pragma unroll
        for (int u = 0; u < 2; ++u)
            pw[u] = (nrow < MLPH)
                ? *(const float4*)&W1[nrow * DD + wofs + hc + (wq + 8 * u) * 4]
                : make_float4(0.f, 0.f, 0.f, 0.f);
    };
    ld(0);
    v2f acc[2];
    acc[0] = (v2f){0.f, 0.f}; acc[1] = (v2f){0.f, 0.f};

    for (int ch = 0; ch < 6; ++ch) {
        __syncthreads();
        #pragma unroll
        for (int u = 0; u < 4; ++u) {
            int hq = (sq + 4 * u) * 4;
            Ss[hq + 0][srow] = ps[u].x; Ss[hq + 1][srow] = ps[u].y;
            Ss[hq + 2][srow] = ps[u].z; Ss[hq + 3][srow] = ps[u].w;
        }
        #pragma unroll
        for (int u = 0; u < 2; ++u) {
            int hq = (wq + 8 * u) * 4;
            Ws[hq + 0][wrow] = pw[u].x; Ws[hq + 1][wrow] = pw[u].y;
            Ws[hq + 2][wrow] = pw[u].z; Ws[hq + 3][wrow] = pw[u].w;
        }
        __syncthreads();
        if (ch < 5) ld((ch + 1) * 64);
        #pragma unroll
        for (int h = 0; h < 64; ++h) {
            v2f sv = *(const v2f*)&Ss[h][bp * 2];   // 16 distinct v2f: CF
            v2f wv = *(const v2f*)&Ws[h][np * 2];   // 4 distinct/wave: bcast
            acc[0] = __builtin_elementwise_fma((v2f){sv.x, sv.x}, wv, acc[0]);
            acc[1] = __builtin_elementwise_fma((v2f){sv.y, sv.y}, wv, acc[1]);
        }
    }
    #pragma unroll
    for (int i = 0; i < 2; ++i) {
        int bb = b0 + bp * 2 + i;
        int n = n0 + np * 2;
        float r0 = 0.f, r1 = 0.f;
        if (n < MLPH)     r0 = acc[i].x + (z ? 0.f : b1[n]);
        if (n + 1 < MLPH) r1 = acc[i].y + (z ? 0.f : b1[n + 1]);
        *(v2f*)&Out[bb * MLPP + n] = (v2f){r0, r1};
    }
}

// ---------------- C: T0 sum — one wave per row, float4 loads ----------------
__global__ __launch_bounds__(256) void k_t0(
    const float* __restrict__ Axb, const float* __restrict__ By,
    const float* __restrict__ W2, const float* __restrict__ b2,
    float* __restrict__ accum)
{
    int tid = threadIdx.x;
    int w = tid >> 6, l = tid & 63;
    int b = blockIdx.x * 4 + w;
    const float4* A4 = (const float4*)(Axb + b * MLPP);
    const float4* B4 = (const float4*)(By + b * MLPP);
    const float4* W4 = (const float4*)W2;
    float t = 0.f;
    {
        float4 a = A4[l], bb = B4[l], ww = W4[l];   // k = 4l, 0..255 < 300
        t = fmaf(fmaxf(a.x + bb.x, 0.f), ww.x, t);
        t = fmaf(fmaxf(a.y + bb.y, 0.f), ww.y, t);
        t = fmaf(fmaxf(a.z + bb.z, 0.f), ww.z, t);
        t = fmaf(fmaxf(a.w + bb.w, 0.f), ww.w, t);
    }
    if (l < 11) {                                   // k = 256+4l, 296..299 max
        float4 a = A4[64 + l], bb = B4[64 + l], ww = W4[64 + l];
        t = fmaf(fmaxf(a.x + bb.x, 0.f), ww.x, t);
        t = fmaf(fmaxf(a.y + bb.y, 0.f), ww.y, t);
        t = fmaf(fmaxf(a.z + bb.z, 0.f), ww.z, t);
        t = fmaf(fmaxf(a.w + bb.w, 0.f), ww.w, t);
    }
    #pragma unroll
    for (int m = 1; m < 64; m <<= 1) t += __shfl_xor(t, m);
    if (l == 0) atomicAdd(&accum[1], softplusf(t + b2[0]));
}

// ---------------- D: pair kernel, 32x32 tiles, 1024 blocks (4/CU, all CUs) ----------------
// r3 ran 256 fat blocks -> 128 CUs busy and LDS-issue-bound. Now: 1024 blocks
// of 256 thr, 4 outputs/thread (2j x 2i), per k per wave: As v2f (16 distinct,
// CF), Bs v2f (4 distinct, bcast), w2 bcast + 6 pk ops. Est ~12us.
__global__ __launch_bounds__(256) void k_pairs(
    const float* __restrict__ Axb, const float* __restrict__ By,
    const int* __restrict__ perm, const float* __restrict__ W2,
    const float* __restrict__ b2, float* __restrict__ sumexp)
{
    __shared__ float As[64][34];   // [k][j]
    __shared__ float Bs[64][34];   // [k][i]
    __shared__ float w2s[MLPP];
    int tid = threadIdx.x;
    int j0 = blockIdx.x * 32;
    int i0 = blockIdx.y * 32;
    for (int t = tid; t < MLPP; t += 256) w2s[t] = (t < MLPH) ? W2[t] : 0.f;
    int row = tid & 31;        // 0..31: j-row for As, i-row for Bs (banks: CF stores)
    int q   = tid >> 5;        // 0..7 -> float4 k-cols q, q+8
    int jp = tid & 15;         // j-pair -> j = j0 + jp*2 + {0,1}
    int ip = tid >> 4;         // 0..15: i-pair -> i = i0 + ip*2 + {0,1}
    int prow = perm[i0 + row];

    float4 pa[2], pb[2];
    auto ld = [&](int kc) {
        #pragma unroll
        for (int u = 0; u < 2; ++u) {
            int kq = (q + 8 * u) * 4;
            pa[u] = *(const float4*)&Axb[(j0 + row) * MLPP + kc + kq];
            pb[u] = *(const float4*)&By[prow * MLPP + kc + kq];
        }
    };
    ld(0);
    v2f acc2[2];               // [i2], j-pair packed
    acc2[0] = (v2f){0.f, 0.f};
    acc2[1] = (v2f){0.f, 0.f};

    for (int ch = 0; ch < 5; ++ch) {
        __syncthreads();
        #pragma unroll
        for (int u = 0; u < 2; ++u) {
            int kq = (q + 8 * u) * 4;
            As[kq + 0][row] = pa[u].x; As[kq + 1][row] = pa[u].y;
            As[kq + 2][row] = pa[u].z; As[kq + 3][row] = pa[u].w;
            Bs[kq + 0][row] = pb[u].x; Bs[kq + 1][row] = pb[u].y;
            Bs[kq + 2][row] = pb[u].z; Bs[kq + 3][row] = pb[u].w;
        }
        __syncthreads();
        if (ch < 4) ld((ch + 1) * 64);
        int kc = ch * 64;
        #pragma unroll
        for (int k = 0; k < 64; ++k) {
            float w = w2s[kc + k];
            v2f wv2 = (v2f){w, w};
            v2f av = *(const v2f*)&As[k][jp * 2];   // CF
            v2f bv = *(const v2f*)&Bs[k][ip * 2];   // bcast (4 distinct/wave)
            v2f t0v = av + (v2f){bv.x, bv.x};
            t0v = __builtin_elementwise_max(t0v, (v2f){0.f, 0.f});
            acc2[0] = __builtin_elementwise_fma(t0v, wv2, acc2[0]);
            v2f t1v = av + (v2f){bv.y, bv.y};
            t1v = __builtin_elementwise_max(t1v, (v2f){0.f, 0.f});
            acc2[1] = __builtin_elementwise_fma(t1v, wv2, acc2[1]);
        }
    }
    float b2v = b2[0];
    #pragma unroll
    for (int i2 = 0; i2 < 2; ++i2) {
        float ssum = (1.f + expf(acc2[i2].x + b2v)) + (1.f + expf(acc2[i2].y + b2v));
        ssum += __shfl_xor(ssum, 1);   // reduce over jp (16-lane groups)
        ssum += __shfl_xor(ssum, 2);
        ssum += __shfl_xor(ssum, 4);
        ssum += __shfl_xor(ssum, 8);
        if (jp == 0) atomicAdd(&sumexp[i0 + ip * 2 + i2], ssum);
    }
}

// ---------------- E: final scalar ----------------
__global__ __launch_bounds__(256) void k_final(
    const float* __restrict__ accum, const float* __restrict__ sumexp,
    float* __restrict__ out)
{
    int tid = threadIdx.x;
    float s = 0.f;
    for (int i = tid; i < BB; i += 256) s += logf(sumexp[i]);
    #pragma unroll
    for (int m = 1; m < 64; m <<= 1) s += __shfl_xor(s, m);
    __shared__ float red[4];
    if ((tid & 63) == 0) red[tid >> 6] = s;
    __syncthreads();
    if (tid == 0) {
        float lse_mean = (red[0] + red[1] + red[2] + red[3]) / (float)BB;
        float d_skl = accum[0] / (2.f * (float)BB);
        float t0_mean = accum[1] / (float)BB;
        float lower = t0_mean - (lse_mean - logf((float)BB));
        out[0] = d_skl - lower;
    }
}

extern "C" void kernel_launch(void* const* d_in, const int* in_sizes, int n_in,
                              void* d_out, int out_size, void* d_ws, size_t ws_size,
                              hipStream_t stream)
{
    const float* zl     = (const float*)d_in[0];
    const float* zv     = (const float*)d_in[1];
    const float* fc_l_w = (const float*)d_in[2];
    const float* fc_l_b = (const float*)d_in[3];
    const float* fc_v_w = (const float*)d_in[4];
    const float* fc_v_b = (const float*)d_in[5];
    const float* W1     = (const float*)d_in[6];
    const float* b1     = (const float*)d_in[7];
    const float* W2     = (const float*)d_in[8];
    const float* b2     = (const float*)d_in[9];
    const float* eps1   = (const float*)d_in[10];
    const float* eps2   = (const float*)d_in[11];
    const int*   perm   = (const int*)d_in[12];
    float* out = (float*)d_out;

    float* ws     = (float*)d_ws;
    float* accum  = ws;                    // 16
    float* sumexp = ws + 16;               // 1024
    float* s1     = ws + 16 + BB;          // B*384
    float* s2     = s1 + BB * HIDV;        // B*384
    float* Axb    = s2 + BB * HIDV;        // B*320
    float* By     = Axb + BB * MLPP;       // B*320

    k_init<<<5, 256, 0, stream>>>(ws);
    k_rs<<<BB, 384, 0, stream>>>(zl, zv, fc_l_w, fc_l_b, fc_v_w, fc_v_b,
                                 eps1, eps2, s1, s2, accum);
    k_gemm<<<dim3(32, 20, 2), 128, 0, stream>>>(s1, s2, W1, b1, Axb, By);
    k_t0<<<256, 256, 0, stream>>>(Axb, By, W2, b2, accum);
    k_pairs<<<dim3(32, 32), 256, 0, stream>>>(Axb, By, perm, W2, b2, sumexp);
    k_final<<<1, 256, 0, stream>>>(accum, sumexp, out);
}

// Round 6
// 309.071 us; speedup vs baseline: 1.1484x; 1.1484x over previous
//
#include <hip/hip_runtime.h>
#include <math.h>

#define BB   1024
#define DD   768
#define HIDV 384
#define MLPH 300
#define MLPP 320   // padded to multiple of 64

typedef float v2f __attribute__((ext_vector_type(2)));

__device__ __forceinline__ float softplusf(float x) {
    return (x > 20.f) ? x : log1pf(expf(x));
}

// ---------------- init: zero accum[16]+sumexp[1024], build padded w2p[320] ----------------
__global__ void k_init(float* __restrict__ ws, const float* __restrict__ W2) {
    int i = blockIdx.x * 256 + threadIdx.x;
    if (i < 16 + BB) ws[i] = 0.f;
    else if (i < 16 + BB + MLPP) {
        int k = i - 16 - BB;
        ws[i] = (k < MLPH) ? W2[k] : 0.f;
    }
}

// ---------------- A: z-reduce + sample + KL (UNCHANGED control since r2) ----------------
// Pinned at ~73us across 18-55% occupancy and two staging styles: per-CU
// streaming cap (~100 L1 misses in flight x ~700ns), not waves. Accepted.
__global__ __launch_bounds__(384, 6) void k_rs(
    const float* __restrict__ zl, const float* __restrict__ zv,
    const float* __restrict__ wl, const float* __restrict__ blp,
    const float* __restrict__ wv, const float* __restrict__ bvp,
    const float* __restrict__ eps1, const float* __restrict__ eps2,
    float* __restrict__ s1, float* __restrict__ s2, float* __restrict__ accum)
{
    __shared__ float SG[768];    // sig1 [0,384), sig2 [384,768)
    __shared__ float MU2[384];
    __shared__ float pr[6];
    int tid = threadIdx.x;       // 0..383
    int b = blockIdx.x;
    int g = tid / 96;            // 0..3
    int c = tid - g * 96;        // 0..95

    const float4* p;
    if (g < 2) p = (const float4*)(zl + (size_t)b * 15360) + ((g & 1) * 96 + c);
    else       p = (const float4*)(zv + (size_t)b * 27648) + ((g & 1) * 96 + c);

    float acc[4] = {0.f, 0.f, 0.f, 0.f};
    if (g < 2) {
        #pragma unroll
        for (int t0 = 0; t0 < 20; t0 += 10) {
            float4 vb[10];
            #pragma unroll
            for (int u = 0; u < 10; ++u) vb[u] = p[(t0 + u) * 192];
            #pragma unroll
            for (int u = 0; u < 10; ++u) {
                float w = wl[t0 + u];
                acc[0] = fmaf(vb[u].x, w, acc[0]);
                acc[1] = fmaf(vb[u].y, w, acc[1]);
                acc[2] = fmaf(vb[u].z, w, acc[2]);
                acc[3] = fmaf(vb[u].w, w, acc[3]);
            }
        }
    } else {
        #pragma unroll
        for (int t0 = 0; t0 < 36; t0 += 9) {
            float4 vb[9];
            #pragma unroll
            for (int u = 0; u < 9; ++u) vb[u] = p[(t0 + u) * 192];
            #pragma unroll
            for (int u = 0; u < 9; ++u) {
                float w = wv[t0 + u];
                acc[0] = fmaf(vb[u].x, w, acc[0]);
                acc[1] = fmaf(vb[u].y, w, acc[1]);
                acc[2] = fmaf(vb[u].z, w, acc[2]);
                acc[3] = fmaf(vb[u].w, w, acc[3]);
            }
        }
    }

    float bl = blp[0], bv = bvp[0];

    if (g == 1) {                 // sig1
        float4 o;
        o.x = softplusf(acc[0] + bl) + 1e-7f;
        o.y = softplusf(acc[1] + bl) + 1e-7f;
        o.z = softplusf(acc[2] + bl) + 1e-7f;
        o.w = softplusf(acc[3] + bl) + 1e-7f;
        *(float4*)(SG + c * 4) = o;
    } else if (g == 2) {          // mu2
        *(float4*)(MU2 + c * 4) =
            make_float4(acc[0] + bv, acc[1] + bv, acc[2] + bv, acc[3] + bv);
    } else if (g == 3) {          // sig2
        float4 o;
        o.x = softplusf(acc[0] + bv) + 1e-7f;
        o.y = softplusf(acc[1] + bv) + 1e-7f;
        o.z = softplusf(acc[2] + bv) + 1e-7f;
        o.w = softplusf(acc[3] + bv) + 1e-7f;
        *(float4*)(SG + 384 + c * 4) = o;
    }
    __syncthreads();

    float con = 0.f;
    if (g == 0) {
        float4 e1v = ((const float4*)eps1)[b * 96 + c];
        float4 e2v = ((const float4*)eps2)[b * 96 + c];
        float4 g1 = *(const float4*)(SG + c * 4);
        float4 m2 = *(const float4*)(MU2 + c * 4);
        float4 g2 = *(const float4*)(SG + 384 + c * 4);
        float e1a[4] = {e1v.x, e1v.y, e1v.z, e1v.w};
        float e2a[4] = {e2v.x, e2v.y, e2v.z, e2v.w};
        float g1a[4] = {g1.x, g1.y, g1.z, g1.w};
        float g2a[4] = {g2.x, g2.y, g2.z, g2.w};
        float m2a[4] = {m2.x, m2.y, m2.z, m2.w};
        float s1o[4], s2o[4];
        #pragma unroll
        for (int j = 0; j < 4; ++j) {
            float mu1 = acc[j] + bl;
            float mu2 = m2a[j];
            float sg1 = g1a[j], sg2 = g2a[j];
            float e1 = e1a[j], e2 = e2a[j];
            float sv1 = fmaf(sg1, e1, mu1);
            float sv2 = fmaf(sg2, e2, mu2);
            s1o[j] = sv1; s2o[j] = sv2;
            float z12 = (sv1 - mu2) / sg2;
            float z21 = (sv2 - mu1) / sg1;
            con += -0.5f * (e1 * e1 + e2 * e2) + 0.5f * z12 * z12 + 0.5f * z21 * z21;
        }
        ((float4*)s1)[b * 96 + c] = make_float4(s1o[0], s1o[1], s1o[2], s1o[3]);
        ((float4*)s2)[b * 96 + c] = make_float4(s2o[0], s2o[1], s2o[2], s2o[3]);
    }

    #pragma unroll
    for (int m = 1; m < 64; m <<= 1) con += __shfl_xor(con, m);
    if ((tid & 63) == 0) pr[tid >> 6] = con;
    __syncthreads();
    if (tid == 0)
        atomicAdd(&accum[0], pr[0] + pr[1] + pr[2] + pr[3] + pr[4] + pr[5]);
}

// ---------------- B: Axb = s1 @ W1x^T + b1, By = s2 @ W1y^T ----------------
// LDS-ISSUE model (r1-r4 lesson): per-CU LDS port is the currency. 64b x 32n
// tile, 128 thr, 16 outputs/thread (4b x 4n): per h only 2 x ds_read_b128
// for 16 outputs (0.125 instr/out vs 0.5 before). Est ~8-15us.
__global__ __launch_bounds__(128) void k_gemm(
    const float* __restrict__ s1, const float* __restrict__ s2,
    const float* __restrict__ W1, const float* __restrict__ b1,
    float* __restrict__ Axb, float* __restrict__ By)
{
    __shared__ float Ss[64][68];   // [h][b] 64h x 64b (pad 68: 2-way max)
    __shared__ float Ws[64][36];   // [h][n] 64h x 32n
    int z = blockIdx.z;
    const float* S = z ? s2 : s1;
    float* Out = z ? By : Axb;
    int wofs = z ? HIDV : 0;
    int b0 = blockIdx.x * 64;
    int n0 = blockIdx.y * 32;
    int tid = threadIdx.x;
    int srow = tid >> 1, sq8 = (tid & 1) * 8;   // S loader: b-row, 8 h-quads
    int wrow = tid >> 2, wq4 = (tid & 3) * 4;   // W loader: n-row, 4 h-quads
    int nrow = n0 + wrow;
    int bp = tid & 15, np = tid >> 4;           // outputs: b=b0+bp*4+i, n=n0+np*4+c

    float4 ps[8], pw[4];
    auto ld = [&](int hc) {
        #pragma unroll
        for (int u = 0; u < 8; ++u)
            ps[u] = *(const float4*)&S[(b0 + srow) * HIDV + hc + (sq8 + u) * 4];
        #pragma unroll
        for (int u = 0; u < 4; ++u)
            pw[u] = (nrow < MLPH)
                ? *(const float4*)&W1[nrow * DD + wofs + hc + (wq4 + u) * 4]
                : make_float4(0.f, 0.f, 0.f, 0.f);
    };
    ld(0);
    v2f acc[4][2];
    #pragma unroll
    for (int i = 0; i < 4; ++i) { acc[i][0] = (v2f){0.f,0.f}; acc[i][1] = (v2f){0.f,0.f}; }

    for (int ch = 0; ch < 6; ++ch) {
        __syncthreads();
        #pragma unroll
        for (int u = 0; u < 8; ++u) {
            int h4 = (sq8 + u) * 4;
            Ss[h4 + 0][srow] = ps[u].x; Ss[h4 + 1][srow] = ps[u].y;
            Ss[h4 + 2][srow] = ps[u].z; Ss[h4 + 3][srow] = ps[u].w;
        }
        #pragma unroll
        for (int u = 0; u < 4; ++u) {
            int h4 = (wq4 + u) * 4;
            Ws[h4 + 0][wrow] = pw[u].x; Ws[h4 + 1][wrow] = pw[u].y;
            Ws[h4 + 2][wrow] = pw[u].z; Ws[h4 + 3][wrow] = pw[u].w;
        }
        __syncthreads();
        if (ch < 5) ld((ch + 1) * 64);
        #pragma unroll
        for (int h = 0; h < 64; ++h) {
            float4 sv = *(const float4*)&Ss[h][bp * 4];   // 16 distinct: 2-way, CF
            float4 wv = *(const float4*)&Ws[h][np * 4];   // 4-8 distinct: bcast
            v2f w01 = (v2f){wv.x, wv.y}, w23 = (v2f){wv.z, wv.w};
            float sa[4] = {sv.x, sv.y, sv.z, sv.w};
            #pragma unroll
            for (int i = 0; i < 4; ++i) {
                v2f sb = (v2f){sa[i], sa[i]};
                acc[i][0] = __builtin_elementwise_fma(sb, w01, acc[i][0]);
                acc[i][1] = __builtin_elementwise_fma(sb, w23, acc[i][1]);
            }
        }
    }
    int nbase = n0 + np * 4;
    #pragma unroll
    for (int i = 0; i < 4; ++i) {
        int bb = b0 + bp * 4 + i;
        float va[4] = {acc[i][0].x, acc[i][0].y, acc[i][1].x, acc[i][1].y};
        float o[4];
        #pragma unroll
        for (int c = 0; c < 4; ++c) {
            int n = nbase + c;
            float v = va[c];
            if (!z && n < MLPH) v += b1[n];
            o[c] = (n < MLPH) ? v : 0.f;
        }
        *(float4*)&Out[bb * MLPP + nbase] = make_float4(o[0], o[1], o[2], o[3]);
    }
}

// ---------------- C: T0 sum — one wave per row, float4 loads ----------------
__global__ __launch_bounds__(256) void k_t0(
    const float* __restrict__ Axb, const float* __restrict__ By,
    const float* __restrict__ W2, const float* __restrict__ b2,
    float* __restrict__ accum)
{
    int tid = threadIdx.x;
    int w = tid >> 6, l = tid & 63;
    int b = blockIdx.x * 4 + w;
    const float4* A4 = (const float4*)(Axb + b * MLPP);
    const float4* B4 = (const float4*)(By + b * MLPP);
    const float4* W4 = (const float4*)W2;
    float t = 0.f;
    {
        float4 a = A4[l], bb = B4[l], ww = W4[l];   // k = 4l, 0..255 < 300
        t = fmaf(fmaxf(a.x + bb.x, 0.f), ww.x, t);
        t = fmaf(fmaxf(a.y + bb.y, 0.f), ww.y, t);
        t = fmaf(fmaxf(a.z + bb.z, 0.f), ww.z, t);
        t = fmaf(fmaxf(a.w + bb.w, 0.f), ww.w, t);
    }
    if (l < 11) {                                   // k = 256+4l, 296..299 max
        float4 a = A4[64 + l], bb = B4[64 + l], ww = W4[64 + l];
        t = fmaf(fmaxf(a.x + bb.x, 0.f), ww.x, t);
        t = fmaf(fmaxf(a.y + bb.y, 0.f), ww.y, t);
        t = fmaf(fmaxf(a.z + bb.z, 0.f), ww.z, t);
        t = fmaf(fmaxf(a.w + bb.w, 0.f), ww.w, t);
    }
    #pragma unroll
    for (int m = 1; m < 64; m <<= 1) t += __shfl_xor(t, m);
    if (l == 0) atomicAdd(&accum[1], softplusf(t + b2[0]));
}

// ---------------- D: pair kernel, 64x64 tile, 16 outputs/thread ----------------
// Per k per thread: 2 x ds_read_b128 (A-frag 4j, B-frag 4i) -> 16 outputs.
// w2 via padded global w2p at wave-uniform index -> s_load (off the LDS port).
// Per CU: 4 waves x 320k x 2 x 12cy ~= 31k cy ~= 13us (was ~40-55).
__global__ __launch_bounds__(256) void k_pairs(
    const float* __restrict__ Axb, const float* __restrict__ By,
    const int* __restrict__ perm, const float* __restrict__ w2p,
    const float* __restrict__ b2, float* __restrict__ sumexp)
{
    __shared__ float As[64][68];   // [k][j]
    __shared__ float Bs[64][68];   // [k][i]
    int tid = threadIdx.x;
    int j0 = blockIdx.x * 64;
    int i0 = blockIdx.y * 64;
    int row = tid & 63;        // staging row (j for As, i for Bs)
    int q   = tid >> 6;        // 0..3 -> float4 k-cols q+4u
    int jp = tid & 15;         // j = j0 + jp*4 + {0..3}
    int ip = tid >> 4;         // 0..15: i = i0 + ip*4 + {0..3}
    int prow = perm[i0 + row];

    float4 pa[4], pb[4];
    auto ld = [&](int kc) {
        #pragma unroll
        for (int u = 0; u < 4; ++u) {
            int kq = (q + 4 * u) * 4;   // 0..60
            pa[u] = *(const float4*)&Axb[(j0 + row) * MLPP + kc + kq];
            pb[u] = *(const float4*)&By[prow * MLPP + kc + kq];
        }
    };
    ld(0);
    v2f acc2[4][2];            // [i][j-pair]
    #pragma unroll
    for (int i = 0; i < 4; ++i) { acc2[i][0] = (v2f){0.f,0.f}; acc2[i][1] = (v2f){0.f,0.f}; }

    for (int ch = 0; ch < 5; ++ch) {
        __syncthreads();
        #pragma unroll
        for (int u = 0; u < 4; ++u) {
            int kq = (q + 4 * u) * 4;
            As[kq + 0][row] = pa[u].x; As[kq + 1][row] = pa[u].y;
            As[kq + 2][row] = pa[u].z; As[kq + 3][row] = pa[u].w;
            Bs[kq + 0][row] = pb[u].x; Bs[kq + 1][row] = pb[u].y;
            Bs[kq + 2][row] = pb[u].z; Bs[kq + 3][row] = pb[u].w;
        }
        __syncthreads();
        if (ch < 4) ld((ch + 1) * 64);
        int kc = ch * 64;
        #pragma unroll
        for (int k = 0; k < 64; ++k) {
            float w = w2p[kc + k];                      // uniform -> s_load
            v2f wv2 = (v2f){w, w};
            float4 af = *(const float4*)&As[k][jp * 4]; // 16 distinct: 2-way, CF
            float4 bf = *(const float4*)&Bs[k][ip * 4]; // 4-8 distinct: bcast
            v2f alo = (v2f){af.x, af.y}, ahi = (v2f){af.z, af.w};
            float ba[4] = {bf.x, bf.y, bf.z, bf.w};
            #pragma unroll
            for (int i = 0; i < 4; ++i) {
                v2f bc = (v2f){ba[i], ba[i]};
                v2f t0v = alo + bc;
                t0v = __builtin_elementwise_max(t0v, (v2f){0.f, 0.f});
                acc2[i][0] = __builtin_elementwise_fma(t0v, wv2, acc2[i][0]);
                v2f t1v = ahi + bc;
                t1v = __builtin_elementwise_max(t1v, (v2f){0.f, 0.f});
                acc2[i][1] = __builtin_elementwise_fma(t1v, wv2, acc2[i][1]);
            }
        }
    }
    float b2v = b2[0];
    #pragma unroll
    for (int i = 0; i < 4; ++i) {
        float ssum = (1.f + expf(acc2[i][0].x + b2v)) + (1.f + expf(acc2[i][0].y + b2v))
                   + (1.f + expf(acc2[i][1].x + b2v)) + (1.f + expf(acc2[i][1].y + b2v));
        ssum += __shfl_xor(ssum, 1);   // reduce over jp (16-lane groups)
        ssum += __shfl_xor(ssum, 2);
        ssum += __shfl_xor(ssum, 4);
        ssum += __shfl_xor(ssum, 8);
        if (jp == 0) atomicAdd(&sumexp[i0 + ip * 4 + i], ssum);
    }
}

// ---------------- E: final scalar ----------------
__global__ __launch_bounds__(256) void k_final(
    const float* __restrict__ accum, const float* __restrict__ sumexp,
    float* __restrict__ out)
{
    int tid = threadIdx.x;
    float s = 0.f;
    for (int i = tid; i < BB; i += 256) s += logf(sumexp[i]);
    #pragma unroll
    for (int m = 1; m < 64; m <<= 1) s += __shfl_xor(s, m);
    __shared__ float red[4];
    if ((tid & 63) == 0) red[tid >> 6] = s;
    __syncthreads();
    if (tid == 0) {
        float lse_mean = (red[0] + red[1] + red[2] + red[3]) / (float)BB;
        float d_skl = accum[0] / (2.f * (float)BB);
        float t0_mean = accum[1] / (float)BB;
        float lower = t0_mean - (lse_mean - logf((float)BB));
        out[0] = d_skl - lower;
    }
}

extern "C" void kernel_launch(void* const* d_in, const int* in_sizes, int n_in,
                              void* d_out, int out_size, void* d_ws, size_t ws_size,
                              hipStream_t stream)
{
    const float* zl     = (const float*)d_in[0];
    const float* zv     = (const float*)d_in[1];
    const float* fc_l_w = (const float*)d_in[2];
    const float* fc_l_b = (const float*)d_in[3];
    const float* fc_v_w = (const float*)d_in[4];
    const float* fc_v_b = (const float*)d_in[5];
    const float* W1     = (const float*)d_in[6];
    const float* b1     = (const float*)d_in[7];
    const float* W2     = (const float*)d_in[8];
    const float* b2     = (const float*)d_in[9];
    const float* eps1   = (const float*)d_in[10];
    const float* eps2   = (const float*)d_in[11];
    const int*   perm   = (const int*)d_in[12];
    float* out = (float*)d_out;

    float* ws     = (float*)d_ws;
    float* accum  = ws;                    // 16
    float* sumexp = ws + 16;               // 1024
    float* w2p    = ws + 16 + BB;          // 320 (zero-padded W2)
    float* s1     = w2p + MLPP;            // B*384
    float* s2     = s1 + BB * HIDV;        // B*384
    float* Axb    = s2 + BB * HIDV;        // B*320
    float* By     = Axb + BB * MLPP;       // B*320

    k_init<<<6, 256, 0, stream>>>(ws, W2);
    k_rs<<<BB, 384, 0, stream>>>(zl, zv, fc_l_w, fc_l_b, fc_v_w, fc_v_b,
                                 eps1, eps2, s1, s2, accum);
    k_gemm<<<dim3(16, 10, 2), 128, 0, stream>>>(s1, s2, W1, b1, Axb, By);
    k_t0<<<256, 256, 0, stream>>>(Axb, By, W2, b2, accum);
    k_pairs<<<dim3(16, 16), 256, 0, stream>>>(Axb, By, perm, w2p, b2, sumexp);
    k_final<<<1, 256, 0, stream>>>(accum, sumexp, out);
}